// Round 14
// baseline (27.420 us; speedup 1.0000x reference)
//
#include <hip/hip_runtime.h>
#include <stdint.h>

#define B_ 16
#define L_ 256
#define D_ 1024
#define R_ 128
#define M_ (B_*L_)   // 4096 rows of t

typedef short short8 __attribute__((ext_vector_type(8)));
typedef float f32x4 __attribute__((ext_vector_type(4)));

__device__ __forceinline__ unsigned short f2bf(float f) {
  union { float f; unsigned int u; } v; v.f = f;
  unsigned int r = v.u + 0x7FFFu + ((v.u >> 16) & 1u);  // RNE
  return (unsigned short)(r >> 16);
}
__device__ __forceinline__ float bf2f(unsigned short s) {
  union { unsigned int u; float f; } v; v.u = ((unsigned int)s) << 16;
  return v.f;
}
__device__ __forceinline__ void gload_lds16(const void* g, void* l) {
  __builtin_amdgcn_global_load_lds(
      (const __attribute__((address_space(1))) unsigned int*)g,
      (__attribute__((address_space(3))) unsigned int*)l, 16, 0, 0);
}

// ---------------- K1: t = X @ P  (bf16 MFMA), P transposed+cast in-kernel ------
// BM=16, BN=64, BK=128. grid=512, 2 blocks/CU, LDS 40KB. K0 is DELETED:
// P is reg-staged from the original f32 [k][n] layout; one v_cvt_pk_bf16_f32
// per (k,k+1) pair writes the bf16 k-pair into the SAME swizzled sP layout the
// proven compute phase reads. No manual vmcnt: all staging is reg-dependency
// tracked (compiler counted waits); per-iter sync = lgkmcnt(0)+s_barrier only.
__global__ __launch_bounds__(256) void k1_gemm(
    const float* __restrict__ X, const float* __restrict__ P,
    unsigned short* __restrict__ Tb) {
  __shared__ unsigned short sX[2][16 * 128];    // 2 x 4KB, swizzled 256B rows
  __shared__ unsigned short sP[2][64 * 128];    // 2 x 16KB, swizzled 256B rows

  const int tid  = threadIdx.x;
  const int lane = tid & 63;
  const int w    = tid >> 6;          // wave 0..3
  // XCD-bijective swizzle (512 % 8 == 0)
  const int lb   = (blockIdx.x & 7) * 64 + (blockIdx.x >> 3);
  const int m0   = (lb >> 1) * 16;
  const int nb0  = (lb & 1) * 64;

  f32x4 acc;
  acc[0] = 0.f; acc[1] = 0.f; acc[2] = 0.f; acc[3] = 0.f;

  float4 xs[2][2];      // X prefetch: 2 slots x 2 chunks
  float4 ps[2][8];      // P prefetch: 2 slots x 4 (lo,hi) pairs

  // chunk mapping for P: c in [0,1024): kp=(c>>8)*16+(c&15) (k-pair 0..63),
  // nq=(c>>4)&15 (n-quad 0..15). 16 lanes share nq -> consecutive kp.
  auto loadX = [&](float4* slot, int kt) {
#pragma unroll
    for (int i = 0; i < 2; ++i) {
      int c = tid + 256 * i;
      int row = c >> 5, kq = (c & 31) * 4;
      slot[i] = *reinterpret_cast<const float4*>(&X[(size_t)(m0 + row) * D_ + kt * 128 + kq]);
    }
  };
  auto writeX = [&](int buf, const float4* slot) {
#pragma unroll
    for (int i = 0; i < 2; ++i) {
      int c = tid + 256 * i;
      int row = c >> 5, kq = (c & 31) * 4;
      uint2 p;
      p.x = (unsigned int)f2bf(slot[i].x) | ((unsigned int)f2bf(slot[i].y) << 16);
      p.y = (unsigned int)f2bf(slot[i].z) | ((unsigned int)f2bf(slot[i].w) << 16);
      int byte_in_row = (kq * 2) ^ ((row & 7) << 4);
      *reinterpret_cast<uint2*>(reinterpret_cast<char*>(&sX[buf][0]) + row * 256 + byte_in_row) = p;
    }
  };
  auto loadP = [&](float4* slot, int kt) {
    const int k0 = kt * 128;
#pragma unroll
    for (int i = 0; i < 4; ++i) {
      int c = tid + 256 * i;
      int kp = ((c >> 8) << 4) | (c & 15);
      int nq = (c >> 4) & 15;
      const float* base = &P[(size_t)(k0 + 2 * kp) * R_ + nb0 + 4 * nq];
      slot[2 * i]     = *reinterpret_cast<const float4*>(base);        // k = 2kp
      slot[2 * i + 1] = *reinterpret_cast<const float4*>(base + R_);   // k = 2kp+1
    }
  };
  auto writeP = [&](int buf, const float4* slot) {
    char* spb = reinterpret_cast<char*>(&sP[buf][0]);
#pragma unroll
    for (int i = 0; i < 4; ++i) {
      int c = tid + 256 * i;
      int kp = ((c >> 8) << 4) | (c & 15);
      int nq = (c >> 4) & 15;
      const float* lo = reinterpret_cast<const float*>(&slot[2 * i]);
      const float* hi = reinterpret_cast<const float*>(&slot[2 * i + 1]);
#pragma unroll
      for (int e = 0; e < 4; ++e) {
        int row = 4 * nq + e;
        unsigned int pk;
        asm("v_cvt_pk_bf16_f32 %0, %1, %2" : "=v"(pk) : "v"(lo[e]), "v"(hi[e]));
        int byte_in_row = (4 * kp) ^ ((row & 7) << 4);
        *reinterpret_cast<unsigned int*>(spb + row * 256 + byte_in_row) = pk;
      }
    }
  };
  auto compute = [&](int buf) {   // byte-identical to the proven R7 compute
    const char* xb = reinterpret_cast<const char*>(&sX[buf][0]);
    const char* pb = reinterpret_cast<const char*>(&sP[buf][0]);
#pragma unroll
    for (int s = 0; s < 4; ++s) {
      int koffb = s * 64 + ((lane >> 4) << 4);
      int ar = lane & 15;
      short8 a = *reinterpret_cast<const short8*>(xb + ar * 256 + (koffb ^ ((ar & 7) << 4)));
      int br = w * 16 + (lane & 15);
      short8 b = *reinterpret_cast<const short8*>(pb + br * 256 + (koffb ^ ((br & 7) << 4)));
      acc = __builtin_amdgcn_mfma_f32_16x16x32_bf16(a, b, acc, 0, 0, 0);
    }
  };

  // prologue: stage tile 0; prefetch tile 1 into regs (stays in flight)
  loadP(ps[0], 0);
  loadX(xs[0], 0);
  writeP(0, ps[0]);        // compiler counted-waits ps[0] loads only
  writeX(0, xs[0]);
  loadP(ps[1], 1);
  loadX(xs[1], 1);

#pragma unroll
  for (int kt = 0; kt < 8; ++kt) {
    const int buf = kt & 1;
    // publish last iter's ds_writes + retire last iter's ds_reads; then barrier.
    // In-flight global loads (next tiles) are NOT drained (no vmcnt here).
    asm volatile("s_waitcnt lgkmcnt(0)" ::: "memory");
    __builtin_amdgcn_sched_barrier(0);
    __builtin_amdgcn_s_barrier();
    __builtin_amdgcn_sched_barrier(0);
    compute(buf);
    // stage tile kt+1 into buf^1 (its readers finished before barrier@kt);
    // then prefetch tile kt+2 into the freed register slot.
    if (kt < 7) { writeP(buf ^ 1, ps[(kt + 1) & 1]); writeX(buf ^ 1, xs[(kt + 1) & 1]); }
    if (kt < 6) { loadP(ps[kt & 1], kt + 2); loadX(xs[kt & 1], kt + 2); }
  }

  // epilogue: write bf16 t
  const int col = lane & 15;
#pragma unroll
  for (int q = 0; q < 4; ++q) {
    int row = ((lane >> 4) << 2) + q;
    Tb[(size_t)(m0 + row) * R_ + nb0 + w * 16 + col] = f2bf(acc[q]);
  }
}

// ---------------- K2: per-batch Gram + distance epilogue ----------------
// block = (b, i-tile it, j-quarter jq). grid=1024 -> 4 blocks/CU. (R7 verbatim.)
__global__ __launch_bounds__(256) void k2_gram(
    const unsigned short* __restrict__ Tb, float* __restrict__ Out) {
  __shared__ unsigned short sI[16 * 128];    // 4KB, swizzled 256B rows
  __shared__ unsigned short sJ[64 * 128];    // 16KB
  __shared__ float nI[16], nJ[64];

  const int tid  = threadIdx.x;
  const int lane = tid & 63;
  const int w    = tid >> 6;        // 0..3
  const int blk  = blockIdx.x;
  const int b    = blk >> 6;
  const int it   = (blk >> 2) & 15;
  const int jq   = blk & 3;

  // stage sI: 256 chunks of 16B (1/thread)
  {
    int row = tid >> 4, ch = tid & 15;
    gload_lds16(&Tb[(size_t)(b * L_ + it * 16 + row) * R_ + ((ch ^ (row & 7)) * 8)],
                reinterpret_cast<char*>(sI) + tid * 16);
  }
  // stage sJ: 1024 chunks (4/thread)
#pragma unroll
  for (int i = 0; i < 4; ++i) {
    int c = tid + 256 * i;
    int row = c >> 4, ch = c & 15;
    gload_lds16(&Tb[(size_t)(b * L_ + jq * 64 + row) * R_ + ((ch ^ (row & 7)) * 8)],
                reinterpret_cast<char*>(sJ) + c * 16);
  }
  __syncthreads();

  // norms: threads 0..159, row = t>>1 (0..15 -> sI, 16..79 -> sJ), half = t&1
  if (tid < 160) {
    int row = tid >> 1, h = tid & 1;
    const char* base = (row < 16) ? reinterpret_cast<const char*>(sI)
                                  : reinterpret_cast<const char*>(sJ);
    int r = (row < 16) ? row : row - 16;
    float s = 0.f;
#pragma unroll
    for (int j = 0; j < 8; ++j) {
      short8 v = *reinterpret_cast<const short8*>(base + r * 256 + ((h * 128 + j * 16) ^ ((r & 7) << 4)));
#pragma unroll
      for (int e = 0; e < 8; ++e) { float f = bf2f((unsigned short)v[e]); s += f * f; }
    }
    s += __shfl_xor(s, 1);
    if (h == 0) { if (row < 16) nI[row] = s; else nJ[row - 16] = s; }
  }

  // Gram via MFMA
  f32x4 acc;
  acc[0] = 0.f; acc[1] = 0.f; acc[2] = 0.f; acc[3] = 0.f;
  const char* ib = reinterpret_cast<const char*>(sI);
  const char* jb = reinterpret_cast<const char*>(sJ);
#pragma unroll
  for (int s = 0; s < 4; ++s) {
    int koffb = s * 64 + ((lane >> 4) << 4);
    int ar = lane & 15;
    short8 a = *reinterpret_cast<const short8*>(ib + ar * 256 + (koffb ^ ((ar & 7) << 4)));
    int br = w * 16 + (lane & 15);
    short8 bv = *reinterpret_cast<const short8*>(jb + br * 256 + (koffb ^ ((br & 7) << 4)));
    acc = __builtin_amdgcn_mfma_f32_16x16x32_bf16(a, bv, acc, 0, 0, 0);
  }
  __syncthreads();   // nI/nJ visible to all

  const int col = lane & 15;
  const int jj = w * 16 + col;
  const float nj = nJ[jj];
#pragma unroll
  for (int q = 0; q < 4; ++q) {
    int ir = ((lane >> 4) << 2) + q;
    float v = nI[ir] + nj - 2.0f * acc[q];
    Out[(size_t)(b * L_ + it * 16 + ir) * L_ + jq * 64 + jj] = fmaxf(v, 0.0f);
  }
}

extern "C" void kernel_launch(void* const* d_in, const int* in_sizes, int n_in,
                              void* d_out, int out_size, void* d_ws, size_t ws_size,
                              hipStream_t stream) {
  const float* X = (const float*)d_in[0];   // [16,256,1024]
  const float* P = (const float*)d_in[1];   // [1024,128]
  float* Out = (float*)d_out;               // [16,256,256]
  char* ws = (char*)d_ws;
  unsigned short* Tb = (unsigned short*)ws;                                // 1 MB

  k1_gemm<<<M_ / 16 * 2, 256, 0, stream>>>(X, P, Tb);
  k2_gram<<<B_ * 16 * 4, 256, 0, stream>>>(Tb, Out);
}

// Round 15
// 21.674 us; speedup vs baseline: 1.2651x; 1.2651x over previous
//
#include <hip/hip_runtime.h>
#include <stdint.h>

#define B_ 16
#define L_ 256
#define D_ 1024
#define R_ 128
#define M_ (B_*L_)   // 4096 rows of t

typedef short short8 __attribute__((ext_vector_type(8)));
typedef float f32x4 __attribute__((ext_vector_type(4)));

__device__ __forceinline__ unsigned short f2bf(float f) {
  union { float f; unsigned int u; } v; v.f = f;
  unsigned int r = v.u + 0x7FFFu + ((v.u >> 16) & 1u);  // RNE
  return (unsigned short)(r >> 16);
}
__device__ __forceinline__ float bf2f(unsigned short s) {
  union { unsigned int u; float f; } v; v.u = ((unsigned int)s) << 16;
  return v.f;
}
__device__ __forceinline__ void gload_lds16(const void* g, void* l) {
  __builtin_amdgcn_global_load_lds(
      (const __attribute__((address_space(1))) unsigned int*)g,
      (__attribute__((address_space(3))) unsigned int*)l, 16, 0, 0);
}

// ---------------- K1: t = X @ P  (bf16 MFMA), P transposed+cast in-kernel ------
// BM=16, BN=64, BK=128. grid=512, 2 blocks/CU, LDS 40KB. No K0:
// P reg-staged from f32 [k][n] with COALESCED mapping (nq = c&15 across lanes
// -> 16 lanes read 256B contiguous from one k-row; kp = c>>4). One
// v_cvt_pk_bf16_f32 per (k,k+1) pair; swizzled sP write (same involution as
// the proven read side). Per-iter sync = lgkmcnt(0)+sched_barrier+s_barrier;
// global prefetch loads ride across barriers (reg-dependency counted waits).
__global__ __launch_bounds__(256) void k1_gemm(
    const float* __restrict__ X, const float* __restrict__ P,
    unsigned short* __restrict__ Tb) {
  __shared__ unsigned short sX[2][16 * 128];    // 2 x 4KB, swizzled 256B rows
  __shared__ unsigned short sP[2][64 * 128];    // 2 x 16KB, swizzled 256B rows

  const int tid  = threadIdx.x;
  const int lane = tid & 63;
  const int w    = tid >> 6;          // wave 0..3
  // XCD-bijective swizzle (512 % 8 == 0)
  const int lb   = (blockIdx.x & 7) * 64 + (blockIdx.x >> 3);
  const int m0   = (lb >> 1) * 16;
  const int nb0  = (lb & 1) * 64;

  f32x4 acc;
  acc[0] = 0.f; acc[1] = 0.f; acc[2] = 0.f; acc[3] = 0.f;

  float4 xs[2][2];      // X prefetch: 2 slots x 2 chunks
  float4 ps[2][8];      // P prefetch: 2 slots x 4 (lo,hi) row-pairs

  auto loadX = [&](float4* slot, int kt) {
#pragma unroll
    for (int i = 0; i < 2; ++i) {
      int c = tid + 256 * i;
      int row = c >> 5, kq = (c & 31) * 4;
      slot[i] = *reinterpret_cast<const float4*>(&X[(size_t)(m0 + row) * D_ + kt * 128 + kq]);
    }
  };
  auto writeX = [&](int buf, const float4* slot) {
#pragma unroll
    for (int i = 0; i < 2; ++i) {
      int c = tid + 256 * i;
      int row = c >> 5, kq = (c & 31) * 4;
      uint2 p;
      p.x = (unsigned int)f2bf(slot[i].x) | ((unsigned int)f2bf(slot[i].y) << 16);
      p.y = (unsigned int)f2bf(slot[i].z) | ((unsigned int)f2bf(slot[i].w) << 16);
      int byte_in_row = (kq * 2) ^ ((row & 7) << 4);
      *reinterpret_cast<uint2*>(reinterpret_cast<char*>(&sX[buf][0]) + row * 256 + byte_in_row) = p;
    }
  };
  // c in [0,1024): nq = c&15 (n-quad, consecutive across lanes -> coalesced),
  // kp = c>>4 (k-pair 0..63). Lane reads 16B of row k0+2kp and row k0+2kp+1.
  auto loadP = [&](float4* slot, int kt) {
    const int k0 = kt * 128;
#pragma unroll
    for (int i = 0; i < 4; ++i) {
      int c = tid + 256 * i;
      int nq = c & 15;
      int kp = c >> 4;
      const float* base = &P[(size_t)(k0 + 2 * kp) * R_ + nb0 + 4 * nq];
      slot[2 * i]     = *reinterpret_cast<const float4*>(base);        // k = 2kp
      slot[2 * i + 1] = *reinterpret_cast<const float4*>(base + R_);   // k = 2kp+1
    }
  };
  auto writeP = [&](int buf, const float4* slot) {
    char* spb = reinterpret_cast<char*>(&sP[buf][0]);
#pragma unroll
    for (int i = 0; i < 4; ++i) {
      int c = tid + 256 * i;
      int nq = c & 15;
      int kp = c >> 4;
      const float* lo = reinterpret_cast<const float*>(&slot[2 * i]);
      const float* hi = reinterpret_cast<const float*>(&slot[2 * i + 1]);
#pragma unroll
      for (int e = 0; e < 4; ++e) {
        int row = 4 * nq + e;
        unsigned int pk;
        asm("v_cvt_pk_bf16_f32 %0, %1, %2" : "=v"(pk) : "v"(lo[e]), "v"(hi[e]));
        int byte_in_row = (4 * kp) ^ ((row & 7) << 4);
        *reinterpret_cast<unsigned int*>(spb + row * 256 + byte_in_row) = pk;
      }
    }
  };
  auto compute = [&](int buf) {   // byte-identical to the proven R7 compute
    const char* xb = reinterpret_cast<const char*>(&sX[buf][0]);
    const char* pb = reinterpret_cast<const char*>(&sP[buf][0]);
#pragma unroll
    for (int s = 0; s < 4; ++s) {
      int koffb = s * 64 + ((lane >> 4) << 4);
      int ar = lane & 15;
      short8 a = *reinterpret_cast<const short8*>(xb + ar * 256 + (koffb ^ ((ar & 7) << 4)));
      int br = w * 16 + (lane & 15);
      short8 b = *reinterpret_cast<const short8*>(pb + br * 256 + (koffb ^ ((br & 7) << 4)));
      acc = __builtin_amdgcn_mfma_f32_16x16x32_bf16(a, b, acc, 0, 0, 0);
    }
  };

  // prologue: stage tile 0; prefetch tile 1 into regs (stays in flight)
  loadP(ps[0], 0);
  loadX(xs[0], 0);
  writeP(0, ps[0]);        // compiler counted-waits ps[0] loads only
  writeX(0, xs[0]);
  loadP(ps[1], 1);
  loadX(xs[1], 1);

#pragma unroll
  for (int kt = 0; kt < 8; ++kt) {
    const int buf = kt & 1;
    // publish last iter's ds_writes + retire last iter's ds_reads; then barrier.
    // In-flight global loads (next tiles) are NOT drained (no vmcnt here).
    asm volatile("s_waitcnt lgkmcnt(0)" ::: "memory");
    __builtin_amdgcn_sched_barrier(0);
    __builtin_amdgcn_s_barrier();
    __builtin_amdgcn_sched_barrier(0);
    compute(buf);
    // stage tile kt+1 into buf^1 (its readers finished before barrier@kt);
    // then prefetch tile kt+2 into the freed register slot.
    if (kt < 7) { writeP(buf ^ 1, ps[(kt + 1) & 1]); writeX(buf ^ 1, xs[(kt + 1) & 1]); }
    if (kt < 6) { loadP(ps[kt & 1], kt + 2); loadX(xs[kt & 1], kt + 2); }
  }

  // epilogue: write bf16 t
  const int col = lane & 15;
#pragma unroll
  for (int q = 0; q < 4; ++q) {
    int row = ((lane >> 4) << 2) + q;
    Tb[(size_t)(m0 + row) * R_ + nb0 + w * 16 + col] = f2bf(acc[q]);
  }
}

// ---------------- K2: per-batch Gram + distance epilogue ----------------
// block = (b, i-tile it, j-quarter jq). grid=1024 -> 4 blocks/CU. (R7 verbatim.)
__global__ __launch_bounds__(256) void k2_gram(
    const unsigned short* __restrict__ Tb, float* __restrict__ Out) {
  __shared__ unsigned short sI[16 * 128];    // 4KB, swizzled 256B rows
  __shared__ unsigned short sJ[64 * 128];    // 16KB
  __shared__ float nI[16], nJ[64];

  const int tid  = threadIdx.x;
  const int lane = tid & 63;
  const int w    = tid >> 6;        // 0..3
  const int blk  = blockIdx.x;
  const int b    = blk >> 6;
  const int it   = (blk >> 2) & 15;
  const int jq   = blk & 3;

  // stage sI: 256 chunks of 16B (1/thread)
  {
    int row = tid >> 4, ch = tid & 15;
    gload_lds16(&Tb[(size_t)(b * L_ + it * 16 + row) * R_ + ((ch ^ (row & 7)) * 8)],
                reinterpret_cast<char*>(sI) + tid * 16);
  }
  // stage sJ: 1024 chunks (4/thread)
#pragma unroll
  for (int i = 0; i < 4; ++i) {
    int c = tid + 256 * i;
    int row = c >> 4, ch = c & 15;
    gload_lds16(&Tb[(size_t)(b * L_ + jq * 64 + row) * R_ + ((ch ^ (row & 7)) * 8)],
                reinterpret_cast<char*>(sJ) + c * 16);
  }
  __syncthreads();

  // norms: threads 0..159, row = t>>1 (0..15 -> sI, 16..79 -> sJ), half = t&1
  if (tid < 160) {
    int row = tid >> 1, h = tid & 1;
    const char* base = (row < 16) ? reinterpret_cast<const char*>(sI)
                                  : reinterpret_cast<const char*>(sJ);
    int r = (row < 16) ? row : row - 16;
    float s = 0.f;
#pragma unroll
    for (int j = 0; j < 8; ++j) {
      short8 v = *reinterpret_cast<const short8*>(base + r * 256 + ((h * 128 + j * 16) ^ ((r & 7) << 4)));
#pragma unroll
      for (int e = 0; e < 8; ++e) { float f = bf2f((unsigned short)v[e]); s += f * f; }
    }
    s += __shfl_xor(s, 1);
    if (h == 0) { if (row < 16) nI[row] = s; else nJ[row - 16] = s; }
  }

  // Gram via MFMA
  f32x4 acc;
  acc[0] = 0.f; acc[1] = 0.f; acc[2] = 0.f; acc[3] = 0.f;
  const char* ib = reinterpret_cast<const char*>(sI);
  const char* jb = reinterpret_cast<const char*>(sJ);
#pragma unroll
  for (int s = 0; s < 4; ++s) {
    int koffb = s * 64 + ((lane >> 4) << 4);
    int ar = lane & 15;
    short8 a = *reinterpret_cast<const short8*>(ib + ar * 256 + (koffb ^ ((ar & 7) << 4)));
    int br = w * 16 + (lane & 15);
    short8 bv = *reinterpret_cast<const short8*>(jb + br * 256 + (koffb ^ ((br & 7) << 4)));
    acc = __builtin_amdgcn_mfma_f32_16x16x32_bf16(a, bv, acc, 0, 0, 0);
  }
  __syncthreads();   // nI/nJ visible to all

  const int col = lane & 15;
  const int jj = w * 16 + col;
  const float nj = nJ[jj];
#pragma unroll
  for (int q = 0; q < 4; ++q) {
    int ir = ((lane >> 4) << 2) + q;
    float v = nI[ir] + nj - 2.0f * acc[q];
    Out[(size_t)(b * L_ + it * 16 + ir) * L_ + jq * 64 + jj] = fmaxf(v, 0.0f);
  }
}

extern "C" void kernel_launch(void* const* d_in, const int* in_sizes, int n_in,
                              void* d_out, int out_size, void* d_ws, size_t ws_size,
                              hipStream_t stream) {
  const float* X = (const float*)d_in[0];   // [16,256,1024]
  const float* P = (const float*)d_in[1];   // [1024,128]
  float* Out = (float*)d_out;               // [16,256,256]
  char* ws = (char*)d_ws;
  unsigned short* Tb = (unsigned short*)ws;                                // 1 MB

  k1_gemm<<<M_ / 16 * 2, 256, 0, stream>>>(X, P, Tb);
  k2_gram<<<B_ * 16 * 4, 256, 0, stream>>>(Tb, Out);
}

// Round 16
// 20.731 us; speedup vs baseline: 1.3226x; 1.0455x over previous
//
#include <hip/hip_runtime.h>
#include <stdint.h>

#define B_ 16
#define L_ 256
#define D_ 1024
#define R_ 128
#define M_ (B_*L_)   // 4096 rows of t

typedef short short8 __attribute__((ext_vector_type(8)));
typedef float f32x4 __attribute__((ext_vector_type(4)));

__device__ __forceinline__ unsigned short f2bf(float f) {
  union { float f; unsigned int u; } v; v.f = f;
  unsigned int r = v.u + 0x7FFFu + ((v.u >> 16) & 1u);  // RNE
  return (unsigned short)(r >> 16);
}
__device__ __forceinline__ float bf2f(unsigned short s) {
  union { unsigned int u; float f; } v; v.u = ((unsigned int)s) << 16;
  return v.f;
}
__device__ __forceinline__ void gload_lds16(const void* g, void* l) {
  __builtin_amdgcn_global_load_lds(
      (const __attribute__((address_space(1))) unsigned int*)g,
      (__attribute__((address_space(3))) unsigned int*)l, 16, 0, 0);
}

// ---------------- K0: P [1024][128] f32 -> PbT [128][1024] bf16 ----------------
// 128 blocks: each thread does a k-QUAD (4 strided loads + 8B store).
__global__ __launch_bounds__(256) void k0_transpose_cast(
    const float* __restrict__ P, unsigned short* __restrict__ PbT) {
  int id = blockIdx.x * 256 + threadIdx.x;   // 0..32767
  int n  = id & 127;                         // consecutive across lanes
  int kq = id >> 7;                          // quad of k: 0..255
  union { unsigned short s[4]; uint2 v; } u;
#pragma unroll
  for (int j = 0; j < 4; ++j) u.s[j] = f2bf(P[(kq * 4 + j) * R_ + n]);
  *reinterpret_cast<uint2*>(&PbT[(size_t)n * D_ + kq * 4]) = u.v;
}

// ---------------- K1: t = X @ P  (bf16 MFMA) ----------------
// BM=16, BN=64, BK=128. grid=512, 2 blocks/CU.  (R7 structure, best measured.)
// Counted-vmcnt pipeline, race-free placement: ALL staging into buf^1 happens
// AFTER barrier@kt. Per-iter: waitcnt(vmcnt 2, lgkm 0) -> barrier -> compute(buf)
//                 -> issueP(buf^1) -> loadX(kt+2) -> writeX(buf^1).
__global__ __launch_bounds__(256) void k1_gemm(
    const float* __restrict__ X, const unsigned short* __restrict__ PbT,
    unsigned short* __restrict__ Tb) {
  __shared__ unsigned short sX[2][16 * 128];    // 2 x 4KB, swizzled 256B rows
  __shared__ unsigned short sP[2][64 * 128];    // 2 x 16KB, swizzled 256B rows

  const int tid  = threadIdx.x;
  const int lane = tid & 63;
  const int w    = tid >> 6;          // wave 0..3
  // XCD-bijective swizzle (512 % 8 == 0)
  const int lb   = (blockIdx.x & 7) * 64 + (blockIdx.x >> 3);
  const int m0   = (lb >> 1) * 16;
  const int nb0  = (lb & 1) * 64;

  f32x4 acc;
  acc[0] = 0.f; acc[1] = 0.f; acc[2] = 0.f; acc[3] = 0.f;

  float4 xs[2][2];   // 2 prefetch slots x 2 chunks (statically indexed under unroll)

  auto loadX = [&](float4* slot, int kt) {
#pragma unroll
    for (int i = 0; i < 2; ++i) {
      int c = tid + 256 * i;
      int row = c >> 5, kq = (c & 31) * 4;
      slot[i] = *reinterpret_cast<const float4*>(&X[(size_t)(m0 + row) * D_ + kt * 128 + kq]);
    }
  };
  auto writeX = [&](int buf, const float4* slot) {
#pragma unroll
    for (int i = 0; i < 2; ++i) {
      int c = tid + 256 * i;
      int row = c >> 5, kq = (c & 31) * 4;
      uint2 p;
      p.x = (unsigned int)f2bf(slot[i].x) | ((unsigned int)f2bf(slot[i].y) << 16);
      p.y = (unsigned int)f2bf(slot[i].z) | ((unsigned int)f2bf(slot[i].w) << 16);
      int byte_in_row = (kq * 2) ^ ((row & 7) << 4);
      *reinterpret_cast<uint2*>(reinterpret_cast<char*>(&sX[buf][0]) + row * 256 + byte_in_row) = p;
    }
  };
  auto issueP = [&](int buf, int kt) {
    const int k0 = kt * 128;
#pragma unroll
    for (int i = 0; i < 4; ++i) {
      int c = tid + 256 * i;
      int row = c >> 4, ch = c & 15;   // 16 chunks per 256B row
      gload_lds16(&PbT[(size_t)(nb0 + row) * D_ + k0 + ((ch ^ (row & 7)) * 8)],
                  reinterpret_cast<char*>(&sP[buf][0]) + c * 16);
    }
  };
  auto compute = [&](int buf) {
    const char* xb = reinterpret_cast<const char*>(&sX[buf][0]);
    const char* pb = reinterpret_cast<const char*>(&sP[buf][0]);
#pragma unroll
    for (int s = 0; s < 4; ++s) {
      int koffb = s * 64 + ((lane >> 4) << 4);
      int ar = lane & 15;
      short8 a = *reinterpret_cast<const short8*>(xb + ar * 256 + (koffb ^ ((ar & 7) << 4)));
      int br = w * 16 + (lane & 15);
      short8 b = *reinterpret_cast<const short8*>(pb + br * 256 + (koffb ^ ((br & 7) << 4)));
      acc = __builtin_amdgcn_mfma_f32_16x16x32_bf16(a, b, acc, 0, 0, 0);
    }
  };

  // prologue: issue X(0), P(0), X(1); write sX[0] (compiler counted-waits X(0) only)
  loadX(xs[0], 0);
  issueP(0, 0);
  loadX(xs[1], 1);
  writeX(0, xs[0]);
  // outstanding: P(0)x4, X(1)x2

#pragma unroll
  for (int kt = 0; kt < 8; ++kt) {
    const int buf = kt & 1;
    // retire P(kt) (4 oldest); keep X loads in flight; publish last iter's sX writes
    if (kt == 7) asm volatile("s_waitcnt vmcnt(0) lgkmcnt(0)" ::: "memory");
    else         asm volatile("s_waitcnt vmcnt(2) lgkmcnt(0)" ::: "memory");
    __builtin_amdgcn_sched_barrier(0);
    __builtin_amdgcn_s_barrier();
    compute(buf);
    // staging into buf^1: safe, all waves passed barrier@kt (readers of buf^1 done)
    if (kt < 7) issueP(buf ^ 1, kt + 1);
    if (kt < 6) loadX(xs[kt & 1], kt + 2);
    if (kt < 7) writeX(buf ^ 1, xs[(kt + 1) & 1]);
  }

  // epilogue: write bf16 t
  const int col = lane & 15;
#pragma unroll
  for (int q = 0; q < 4; ++q) {
    int row = ((lane >> 4) << 2) + q;
    Tb[(size_t)(m0 + row) * R_ + nb0 + w * 16 + col] = f2bf(acc[q]);
  }
}

// ---------------- K2: per-batch Gram + distance epilogue ----------------
// block = (b, i-tile it, j-quarter jq). grid=1024 -> 4 blocks/CU. (R7 verbatim.)
__global__ __launch_bounds__(256) void k2_gram(
    const unsigned short* __restrict__ Tb, float* __restrict__ Out) {
  __shared__ unsigned short sI[16 * 128];    // 4KB, swizzled 256B rows
  __shared__ unsigned short sJ[64 * 128];    // 16KB
  __shared__ float nI[16], nJ[64];

  const int tid  = threadIdx.x;
  const int lane = tid & 63;
  const int w    = tid >> 6;        // 0..3
  const int blk  = blockIdx.x;
  const int b    = blk >> 6;
  const int it   = (blk >> 2) & 15;
  const int jq   = blk & 3;

  // stage sI: 256 chunks of 16B (1/thread)
  {
    int row = tid >> 4, ch = tid & 15;
    gload_lds16(&Tb[(size_t)(b * L_ + it * 16 + row) * R_ + ((ch ^ (row & 7)) * 8)],
                reinterpret_cast<char*>(sI) + tid * 16);
  }
  // stage sJ: 1024 chunks (4/thread)
#pragma unroll
  for (int i = 0; i < 4; ++i) {
    int c = tid + 256 * i;
    int row = c >> 4, ch = c & 15;
    gload_lds16(&Tb[(size_t)(b * L_ + jq * 64 + row) * R_ + ((ch ^ (row & 7)) * 8)],
                reinterpret_cast<char*>(sJ) + c * 16);
  }
  __syncthreads();

  // norms: threads 0..159, row = t>>1 (0..15 -> sI, 16..79 -> sJ), half = t&1
  if (tid < 160) {
    int row = tid >> 1, h = tid & 1;
    const char* base = (row < 16) ? reinterpret_cast<const char*>(sI)
                                  : reinterpret_cast<const char*>(sJ);
    int r = (row < 16) ? row : row - 16;
    float s = 0.f;
#pragma unroll
    for (int j = 0; j < 8; ++j) {
      short8 v = *reinterpret_cast<const short8*>(base + r * 256 + ((h * 128 + j * 16) ^ ((r & 7) << 4)));
#pragma unroll
      for (int e = 0; e < 8; ++e) { float f = bf2f((unsigned short)v[e]); s += f * f; }
    }
    s += __shfl_xor(s, 1);
    if (h == 0) { if (row < 16) nI[row] = s; else nJ[row - 16] = s; }
  }

  // Gram via MFMA
  f32x4 acc;
  acc[0] = 0.f; acc[1] = 0.f; acc[2] = 0.f; acc[3] = 0.f;
  const char* ib = reinterpret_cast<const char*>(sI);
  const char* jb = reinterpret_cast<const char*>(sJ);
#pragma unroll
  for (int s = 0; s < 4; ++s) {
    int koffb = s * 64 + ((lane >> 4) << 4);
    int ar = lane & 15;
    short8 a = *reinterpret_cast<const short8*>(ib + ar * 256 + (koffb ^ ((ar & 7) << 4)));
    int br = w * 16 + (lane & 15);
    short8 bv = *reinterpret_cast<const short8*>(jb + br * 256 + (koffb ^ ((br & 7) << 4)));
    acc = __builtin_amdgcn_mfma_f32_16x16x32_bf16(a, bv, acc, 0, 0, 0);
  }
  __syncthreads();   // nI/nJ visible to all

  const int col = lane & 15;
  const int jj = w * 16 + col;
  const float nj = nJ[jj];
#pragma unroll
  for (int q = 0; q < 4; ++q) {
    int ir = ((lane >> 4) << 2) + q;
    float v = nI[ir] + nj - 2.0f * acc[q];
    Out[(size_t)(b * L_ + it * 16 + ir) * L_ + jq * 64 + jj] = fmaxf(v, 0.0f);
  }
}

extern "C" void kernel_launch(void* const* d_in, const int* in_sizes, int n_in,
                              void* d_out, int out_size, void* d_ws, size_t ws_size,
                              hipStream_t stream) {
  const float* X = (const float*)d_in[0];   // [16,256,1024]
  const float* P = (const float*)d_in[1];   // [1024,128]
  float* Out = (float*)d_out;               // [16,256,256]
  char* ws = (char*)d_ws;
  unsigned short* PbT = (unsigned short*)ws;                               // 256 KB
  unsigned short* Tb  = (unsigned short*)(ws + (size_t)R_ * D_ * 2);       // 1 MB

  k0_transpose_cast<<<128, 256, 0, stream>>>(P, PbT);
  k1_gemm<<<M_ / 16 * 2, 256, 0, stream>>>(X, PbT, Tb);
  k2_gram<<<B_ * 16 * 4, 256, 0, stream>>>(Tb, Out);
}